// Round 8
// baseline (710.922 us; speedup 1.0000x reference)
//
#include <hip/hip_runtime.h>
#include <math.h>

#define B_N 32768
#define A_N 6
#define H_N 256
#define D_N 128
#define K_N 2048
#define MU 1e-7f
#define CB_N 4          // code-dimension split of vq_mfma
#define CPC (K_N / CB_N)

typedef __attribute__((ext_vector_type(8))) short bf16x8;
typedef __attribute__((ext_vector_type(4))) float f32x4;

// Block compiler from contracting a*a into subsequent adds (np computes z*z array, then sums it)
__device__ __forceinline__ float sqf(float v) {
    float s = v * v;
    asm volatile("" : "+v"(s));
    return s;
}

// numpy pairwise_sum for n=128 contiguous fp32: 8 accumulators stride-8 + fixed 3-level tree.
// Bitwise replication of np.sum(x*x, axis=-1). PROTECTED SEMANTICS: do not alter the add order.
__device__ __forceinline__ float np_sumsq_128(const float* __restrict__ p)
{
    float r[8];
#pragma unroll
    for (int j = 0; j < 8; j++) r[j] = sqf(p[j]);
#pragma unroll
    for (int i = 8; i < 128; i += 8) {
#pragma unroll
        for (int j = 0; j < 8; j++) r[j] = r[j] + sqf(p[i + j]);
    }
    return ((r[0] + r[1]) + (r[2] + r[3])) + ((r[4] + r[5]) + (r[6] + r[7]));
}

__global__ __launch_bounds__(256) void rowsum_kernel(const float* __restrict__ z,
                                                     float* __restrict__ az2)
{
    int r = blockIdx.x * 256 + threadIdx.x;
    az2[r] = np_sumsq_128(z + (long)r * D_N);
}

__global__ __launch_bounds__(256) void embsum_kernel(const float* __restrict__ emb,
                                                     float* __restrict__ e2)
{
    int k = blockIdx.x * 256 + threadIdx.x;
    e2[k] = np_sumsq_128(emb + (long)k * D_N);
}

// ---------------- encoder layer 1 (protected fp32 fmaf chain) ----------------
__global__ __launch_bounds__(256) void enc1_kernel(const float* __restrict__ action,
    const float* __restrict__ W, const float* __restrict__ bias, float* __restrict__ out)
{
    __shared__ float as[8][6];
    int tid = threadIdx.x;
    int row0 = blockIdx.x * 8;
    if (tid < 48) as[tid / 6][tid % 6] = action[(long)(row0 + tid / 6) * A_N + tid % 6];
    __syncthreads();
    int col = tid;
    float w[6];
#pragma unroll
    for (int k = 0; k < 6; k++) w[k] = W[k * H_N + col];
    float bv = bias[col];
#pragma unroll
    for (int r = 0; r < 8; r++) {
        float acc = bv;
#pragma unroll
        for (int k = 0; k < 6; k++) acc = fmaf(as[r][k], w[k], acc);
        out[(long)(row0 + r) * H_N + col] = fmaxf(acc, 0.0f);
    }
}

// ---------------- register-tiled fp32 GEMM (R5 configuration, 128x128, 8x8) ----------------
// Per-acc chain: one fmaf per k, ascending == OpenBLAS semantics (z bits PROTECTED).
template<int RELU, int GATHER>
__global__ __launch_bounds__(256) void gemm_rt(const float* __restrict__ Amat,
    const float* __restrict__ W, const float* __restrict__ bias,
    float* __restrict__ Omat, int Kdim, int N, const int* __restrict__ gidx)
{
    __shared__ float As[16][132];   // k-major: As[k][row]
    __shared__ float Bs[16][132];   // k-major: Bs[k][col]
    int tid = threadIdx.x;
    int tx = tid & 15, ty = tid >> 4;
    int row0 = blockIdx.y * 128;
    int col0 = blockIdx.x * 128;
    float acc[8][8];
#pragma unroll
    for (int i = 0; i < 8; i++)
#pragma unroll
        for (int j = 0; j < 8; j++) acc[i][j] = 0.0f;

    for (int k0 = 0; k0 < Kdim; k0 += 16) {
        for (int f = tid; f < 512; f += 256) {
            int r = f >> 2, k4 = (f & 3) * 4;
            long arow = row0 + r;
            long abase = GATHER ? (long)gidx[arow] * Kdim : arow * (long)Kdim;
            float4 v = *(const float4*)&Amat[abase + k0 + k4];
            As[k4 + 0][r] = v.x; As[k4 + 1][r] = v.y; As[k4 + 2][r] = v.z; As[k4 + 3][r] = v.w;
        }
        for (int f = tid; f < 512; f += 256) {
            int kr = f >> 5, c4 = (f & 31) * 4;
            *(float4*)&Bs[kr][c4] = *(const float4*)&W[(long)(k0 + kr) * N + col0 + c4];
        }
        __syncthreads();
#pragma unroll
        for (int kk = 0; kk < 16; kk++) {
            float4 a0 = *(const float4*)&As[kk][ty * 8];
            float4 a1 = *(const float4*)&As[kk][ty * 8 + 4];
            float4 b0 = *(const float4*)&Bs[kk][tx * 4];
            float4 b1 = *(const float4*)&Bs[kk][64 + tx * 4];
            float av[8] = {a0.x, a0.y, a0.z, a0.w, a1.x, a1.y, a1.z, a1.w};
            float bv[8] = {b0.x, b0.y, b0.z, b0.w, b1.x, b1.y, b1.z, b1.w};
#pragma unroll
            for (int i = 0; i < 8; i++)
#pragma unroll
                for (int j = 0; j < 8; j++)
                    acc[i][j] = fmaf(av[i], bv[j], acc[i][j]);
        }
        __syncthreads();
    }
#pragma unroll
    for (int i = 0; i < 8; i++) {
        long r = row0 + ty * 8 + i;
        int c0 = col0 + tx * 4;
        int c1 = col0 + 64 + tx * 4;
        float4 o0, o1;
        o0.x = acc[i][0] + bias[c0 + 0];
        o0.y = acc[i][1] + bias[c0 + 1];
        o0.z = acc[i][2] + bias[c0 + 2];
        o0.w = acc[i][3] + bias[c0 + 3];
        o1.x = acc[i][4] + bias[c1 + 0];
        o1.y = acc[i][5] + bias[c1 + 1];
        o1.z = acc[i][6] + bias[c1 + 2];
        o1.w = acc[i][7] + bias[c1 + 3];
        if (RELU) {
            o0.x = fmaxf(o0.x, 0.0f); o0.y = fmaxf(o0.y, 0.0f);
            o0.z = fmaxf(o0.z, 0.0f); o0.w = fmaxf(o0.w, 0.0f);
            o1.x = fmaxf(o1.x, 0.0f); o1.y = fmaxf(o1.y, 0.0f);
            o1.z = fmaxf(o1.z, 0.0f); o1.w = fmaxf(o1.w, 0.0f);
        }
        *(float4*)&Omat[r * N + c0] = o0;
        *(float4*)&Omat[r * N + c1] = o1;
    }
}

// ---------------- bf16 hi/lo split (x = hi + lo exactly representable pieces) ----------------
__device__ __forceinline__ unsigned short f2bf(float x) {
    unsigned u = __float_as_uint(x);
    u += 0x7fffu + ((u >> 16) & 1u);
    return (unsigned short)(u >> 16);
}
__device__ __forceinline__ float bf2f(unsigned short h) {
    return __uint_as_float(((unsigned)h) << 16);
}

__global__ __launch_bounds__(256) void split_kernel(const float* __restrict__ x,
    short* __restrict__ xh, short* __restrict__ xl)
{
    long i = (long)blockIdx.x * 256 + threadIdx.x;
    float4 v = *(const float4*)&x[i * 4];
    float vv[4] = {v.x, v.y, v.z, v.w};
    short hs[4], ls[4];
#pragma unroll
    for (int j = 0; j < 4; j++) {
        unsigned short h = f2bf(vv[j]);
        hs[j] = (short)h;
        ls[j] = (short)f2bf(vv[j] - bf2f(h));
    }
    ((short4*)xh)[i] = make_short4(hs[0], hs[1], hs[2], hs[3]);
    ((short4*)xl)[i] = make_short4(ls[0], ls[1], ls[2], ls[3]);
}

// lex (v,i) insert into sorted top-3
__device__ __forceinline__ void ins3(float bv, int bi,
    float& v1, int& i1, float& v2, int& i2, float& v3, int& i3)
{
    if (bv < v3 || (bv == v3 && bi < i3)) {
        if (bv < v2 || (bv == v2 && bi < i2)) {
            v3 = v2; i3 = i2;
            if (bv < v1 || (bv == v1 && bi < i1)) { v2 = v1; i2 = i1; v1 = bv; i1 = bi; }
            else { v2 = bv; i2 = bi; }
        } else { v3 = bv; i3 = bi; }
    }
}

// ---------------- VQ candidate generation via bf16-split MFMA (layout validated R7) ----------
// dot' = zh.eh + zh.el + zl.eh; s' = (az2+e2) - 2 dot'; |s'-s| <= ~1e-9 << MU.
// Code dim split CB_N ways across blockIdx.x; per-(row,cb) exact top-3 of s' -> tw.
// launch_bounds(256,3): VGPR cap ~170 so the resident A-frags + top-3 state DON'T spill
// (R7 failure: default bounds capped at 52 VGPR -> scratch thrash, 23 MB WRITE_SIZE).
__global__ __launch_bounds__(256, 3) void vq_mfma(const short* __restrict__ zh,
    const short* __restrict__ zl, const short* __restrict__ eh, const short* __restrict__ el,
    const float* __restrict__ az2, const float* __restrict__ e2,
    float2* __restrict__ tw /* [B][CB_N][3] = (val, idx-bits) */)
{
    int tid = threadIdx.x;
    int wave = tid >> 6, lane = tid & 63;
    int lo = lane & 15, hi = lane >> 4;
    int row0 = blockIdx.y * 64 + wave * 16;
    int code0 = blockIdx.x * CPC;

    // A-frags (z rows), resident. A row = lane&15, k = (lane>>4)*8 + elem, slice ks: k += ks*32.
    bf16x8 ahf0, ahf1, ahf2, ahf3, alf0, alf1, alf2, alf3;
    {
        long o = (long)(row0 + lo) * D_N + hi * 8;
        ahf0 = *(const bf16x8*)&zh[o];       alf0 = *(const bf16x8*)&zl[o];
        ahf1 = *(const bf16x8*)&zh[o + 32];  alf1 = *(const bf16x8*)&zl[o + 32];
        ahf2 = *(const bf16x8*)&zh[o + 64];  alf2 = *(const bf16x8*)&zl[o + 64];
        ahf3 = *(const bf16x8*)&zh[o + 96];  alf3 = *(const bf16x8*)&zl[o + 96];
    }
    // C rows for this lane: row = (lane>>4)*4 + reg, col = lane&15 (code)
    float az_r[4];
#pragma unroll
    for (int r = 0; r < 4; r++) az_r[r] = az2[row0 + hi * 4 + r];

    float v1[4], v2[4], v3[4];
    int   i1[4], i2[4], i3[4];
#pragma unroll
    for (int r = 0; r < 4; r++) { v1[r] = v2[r] = v3[r] = 1e30f; i1[r] = i2[r] = i3[r] = 0; }

#pragma unroll 1
    for (int c = 0; c < CPC / 16; c++) {
        int code = code0 + c * 16 + lo;
        float e2v = e2[code];
        f32x4 ahh = {0.f, 0.f, 0.f, 0.f}, ahl = {0.f, 0.f, 0.f, 0.f}, alh = {0.f, 0.f, 0.f, 0.f};
        long ob = (long)code * D_N + hi * 8;
        bf16x8 bh0 = *(const bf16x8*)&eh[ob];
        bf16x8 bl0 = *(const bf16x8*)&el[ob];
        bf16x8 bh1 = *(const bf16x8*)&eh[ob + 32];
        bf16x8 bl1 = *(const bf16x8*)&el[ob + 32];
        bf16x8 bh2 = *(const bf16x8*)&eh[ob + 64];
        bf16x8 bl2 = *(const bf16x8*)&el[ob + 64];
        bf16x8 bh3 = *(const bf16x8*)&eh[ob + 96];
        bf16x8 bl3 = *(const bf16x8*)&el[ob + 96];
        ahh = __builtin_amdgcn_mfma_f32_16x16x32_bf16(ahf0, bh0, ahh, 0, 0, 0);
        ahl = __builtin_amdgcn_mfma_f32_16x16x32_bf16(ahf0, bl0, ahl, 0, 0, 0);
        alh = __builtin_amdgcn_mfma_f32_16x16x32_bf16(alf0, bh0, alh, 0, 0, 0);
        ahh = __builtin_amdgcn_mfma_f32_16x16x32_bf16(ahf1, bh1, ahh, 0, 0, 0);
        ahl = __builtin_amdgcn_mfma_f32_16x16x32_bf16(ahf1, bl1, ahl, 0, 0, 0);
        alh = __builtin_amdgcn_mfma_f32_16x16x32_bf16(alf1, bh1, alh, 0, 0, 0);
        ahh = __builtin_amdgcn_mfma_f32_16x16x32_bf16(ahf2, bh2, ahh, 0, 0, 0);
        ahl = __builtin_amdgcn_mfma_f32_16x16x32_bf16(ahf2, bl2, ahl, 0, 0, 0);
        alh = __builtin_amdgcn_mfma_f32_16x16x32_bf16(alf2, bh2, alh, 0, 0, 0);
        ahh = __builtin_amdgcn_mfma_f32_16x16x32_bf16(ahf3, bh3, ahh, 0, 0, 0);
        ahl = __builtin_amdgcn_mfma_f32_16x16x32_bf16(ahf3, bl3, ahl, 0, 0, 0);
        alh = __builtin_amdgcn_mfma_f32_16x16x32_bf16(alf3, bh3, alh, 0, 0, 0);
#pragma unroll
        for (int r = 0; r < 4; r++) {
            float dot = (ahh[r] + ahl[r]) + alh[r];
            float s = (az_r[r] + e2v) - 2.0f * dot;
            // in-lane codes ascend -> strict < keeps first-min (lex)
            if (s < v3[r]) {
                if (s < v2[r]) {
                    v3[r] = v2[r]; i3[r] = i2[r];
                    if (s < v1[r]) { v2[r] = v1[r]; i2[r] = i1[r]; v1[r] = s; i1[r] = code; }
                    else { v2[r] = s; i2[r] = code; }
                } else { v3[r] = s; i3[r] = code; }
            }
        }
    }

    // butterfly merge of sorted top-3 triples across the 16 lanes of each row-group
#pragma unroll
    for (int m = 1; m < 16; m <<= 1) {
#pragma unroll
        for (int r = 0; r < 4; r++) {
            float b1 = __shfl_xor(v1[r], m, 16), b2 = __shfl_xor(v2[r], m, 16),
                  b3 = __shfl_xor(v3[r], m, 16);
            int   j1 = __shfl_xor(i1[r], m, 16), j2 = __shfl_xor(i2[r], m, 16),
                  j3 = __shfl_xor(i3[r], m, 16);
            ins3(b1, j1, v1[r], i1[r], v2[r], i2[r], v3[r], i3[r]);
            ins3(b2, j2, v1[r], i1[r], v2[r], i2[r], v3[r], i3[r]);
            ins3(b3, j3, v1[r], i1[r], v2[r], i2[r], v3[r], i3[r]);
        }
    }
    if (lo == 0) {
#pragma unroll
        for (int r = 0; r < 4; r++) {
            long base = ((long)(row0 + hi * 4 + r) * CB_N + blockIdx.x) * 3;
            tw[base + 0] = make_float2(v1[r], __int_as_float(i1[r]));
            tw[base + 1] = make_float2(v2[r], __int_as_float(i2[r]));
            tw[base + 2] = make_float2(v3[r], __int_as_float(i3[r]));
        }
    }
}

// ---------------- merge per-cb top-3s, margin decision + protected exact refine ------------
__global__ __launch_bounds__(256) void vq_pick(const float2* __restrict__ tw,
    const float* __restrict__ z, const float* __restrict__ emb,
    const float* __restrict__ az2, const float* __restrict__ e2,
    int* __restrict__ idxI, float* __restrict__ outIdx,
    int* __restrict__ flaglist, int* __restrict__ flagcnt)
{
    int r = blockIdx.x * 256 + threadIdx.x;
    float v1 = 1e30f, v2 = 1e30f, v3 = 1e30f;
    int   i1 = 0, i2 = 0, i3 = 0;
    for (int cb = 0; cb < CB_N; cb++) {
#pragma unroll
        for (int t = 0; t < 3; t++) {
            float2 c = tw[((long)r * CB_N + cb) * 3 + t];
            ins3(c.x, __float_as_int(c.y), v1, i1, v2, i2, v3, i3);
        }
    }
    int best = i1;
    if (v2 <= v1 + MU) {
        // exact np-fp32 compare of the two leading candidates (protected chain)
        const float* zr = z + (long)r * D_N;
        const float* ea = emb + (long)i1 * D_N;
        const float* eb = emb + (long)i2 * D_N;
        float Ca = 0.0f, Cb = 0.0f;
        for (int d = 0; d < D_N; d++) {
            Ca = fmaf(zr[d], ea[d], Ca);
            Cb = fmaf(zr[d], eb[d], Cb);
        }
        float da = (az2[r] + e2[i1]) - 2.0f * Ca;
        float db = (az2[r] + e2[i2]) - 2.0f * Cb;
        if (db < da || (db == da && i2 < best)) best = i2;
    }
    if (v3 <= v1 + MU) {
        int s = atomicAdd(flagcnt, 1);
        flaglist[s] = r;
    }
    idxI[r] = best;
    outIdx[r] = (float)best;
}

// ---------------- exact full scan for flagged rows (one wave per row) ----------------
__global__ __launch_bounds__(64) void vq_fallback(const float* __restrict__ z,
    const float* __restrict__ emb, const float* __restrict__ az2, const float* __restrict__ e2,
    const int* __restrict__ flaglist, const int* __restrict__ flagcnt,
    int* __restrict__ idxI, float* __restrict__ outIdx)
{
    int n = *flagcnt;
    int lane = threadIdx.x;
    for (int i = blockIdx.x; i < n; i += gridDim.x) {
        int r = flaglist[i];
        const float* zr = z + (long)r * D_N;
        float az = az2[r];
        float bv = 1e30f; int bi = 0;
        for (int c = lane; c < K_N; c += 64) {
            const float* ec = emb + (long)c * D_N;
            float C = 0.0f;
            for (int d = 0; d < D_N; d++) C = fmaf(zr[d], ec[d], C);
            float d2 = (az + e2[c]) - 2.0f * C;
            if (d2 < bv) { bv = d2; bi = c; }   // ascending c: first-min
        }
#pragma unroll
        for (int m = 1; m < 64; m <<= 1) {
            float ov = __shfl_xor(bv, m, 64);
            int   oi = __shfl_xor(bi, m, 64);
            if (ov < bv || (ov == bv && oi < bi)) { bv = ov; bi = oi; }
        }
        if (lane == 0) { idxI[r] = bi; outIdx[r] = (float)bi; }
    }
}

// ---------------- vq loss partial sums ----------------
__global__ __launch_bounds__(256) void vqloss_kernel(const float* __restrict__ z,
    const float* __restrict__ emb, const int* __restrict__ idxI, float* __restrict__ part)
{
    __shared__ float red[256];
    int tid = threadIdx.x;
    int row0 = blockIdx.x * 64;
    float s = 0.0f;
    for (int e = tid; e < 64 * D_N; e += 256) {
        int r = row0 + (e >> 7), d = e & 127;
        float diff = z[(long)r * D_N + d] - emb[(long)idxI[r] * D_N + d];
        s = fmaf(diff, diff, s);
    }
    red[tid] = s; __syncthreads();
    for (int o = 128; o > 0; o >>= 1) { if (tid < o) red[tid] += red[tid + o]; __syncthreads(); }
    if (tid == 0) part[blockIdx.x] = red[0];
}

// ---------------- head: recons = tanh(d2 @ Wh + bh), partial recon loss ----------------
__global__ __launch_bounds__(256) void head_kernel(const float* __restrict__ dbuf,
    const float* __restrict__ Wh, const float* __restrict__ bh,
    const float* __restrict__ action, float* __restrict__ outRec, float* __restrict__ part)
{
    __shared__ float WhS[H_N * A_N];
    __shared__ float red[256];
    int tid = threadIdx.x;
    for (int i = tid; i < H_N * A_N; i += 256) WhS[i] = Wh[i];
    __syncthreads();
    long t = (long)blockIdx.x * 256 + tid;
    int row = (int)(t / 6), col = (int)(t % 6);
    const float* dr = dbuf + (long)row * H_N;
    float acc = bh[col];
    for (int k = 0; k < H_N; k++) acc = fmaf(dr[k], WhS[k * 6 + col], acc);
    float rec = tanhf(acc);
    outRec[t] = rec;
    float diff = rec - action[t];
    red[tid] = diff * diff;
    __syncthreads();
    for (int o = 128; o > 0; o >>= 1) { if (tid < o) red[tid] += red[tid + o]; __syncthreads(); }
    if (tid == 0) part[blockIdx.x] = red[0];
}

// ---------------- finalize scalars ----------------
__global__ void final_kernel(const float* __restrict__ vqp, const float* __restrict__ recp,
                             float* __restrict__ out)
{
    if (threadIdx.x == 0 && blockIdx.x == 0) {
        double vs = 0.0;
        for (int i = 0; i < 512; i++) vs += (double)vqp[i];
        double rs = 0.0;
        for (int i = 0; i < 768; i++) rs += (double)recp[i];
        double m = vs / 4194304.0;           // B*D
        double vql = 1.25 * m;               // beta*commit + embed (forward-equal)
        double rl = rs / 196608.0;           // B*A
        out[0] = (float)(rl + vql);
        out[1] = (float)vql;
        out[2] = (float)rl;
    }
}

extern "C" void kernel_launch(void* const* d_in, const int* in_sizes, int n_in,
                              void* d_out, int out_size, void* d_ws, size_t ws_size,
                              hipStream_t stream)
{
    (void)in_sizes; (void)n_in; (void)out_size; (void)ws_size;
    const float* action = (const float*)d_in[0];
    const float* We1 = (const float*)d_in[1];
    const float* be1 = (const float*)d_in[2];
    const float* We2 = (const float*)d_in[3];
    const float* be2 = (const float*)d_in[4];
    const float* We3 = (const float*)d_in[5];
    const float* be3 = (const float*)d_in[6];
    const float* emb = (const float*)d_in[7];
    const float* Wd1 = (const float*)d_in[8];
    const float* bd1 = (const float*)d_in[9];
    const float* Wd2 = (const float*)d_in[10];
    const float* bd2 = (const float*)d_in[11];
    const float* Wh  = (const float*)d_in[12];
    const float* bh  = (const float*)d_in[13];
    float* out = (float*)d_out;

    // workspace layout (~84 MB):
    //   h1 : B*H floats (33.5 MB) -- aliased as zh/zl/eh/el during VQ (h1 dead post-enc2)
    //   h2 : B*H floats (33.5 MB) -- aliased as tw/flaglist/flagcnt (dead post-enc3)
    //   z  : B*D floats (16.8 MB)
    //   tail: az2(B) e2(K) idxI(B) vqp(512) recp(768)
    float* h1 = (float*)d_ws;
    float* h2 = h1 + (long)B_N * H_N;
    float* z  = h2 + (long)B_N * H_N;
    float* az2 = z + (long)B_N * D_N;
    float* e2  = az2 + B_N;
    int*   idxI = (int*)(e2 + K_N);
    float* vqp  = (float*)(idxI + B_N);
    float* recp = vqp + 512;

    short* zh = (short*)h1;                 // 8.4 MB
    short* zl = zh + (long)B_N * D_N;       // 8.4 MB
    short* eh = zl + (long)B_N * D_N;       // 0.5 MB
    short* el = eh + (long)K_N * D_N;       // 0.5 MB
    float2* tw = (float2*)h2;               // B*CB_N*3 float2 = 3.1 MB
    int* flaglist = (int*)(tw + (long)B_N * CB_N * 3);  // B ints
    int* flagcnt  = flaglist + B_N;                     // 1

    // encoder (protected fp32 chains)
    enc1_kernel<<<B_N / 8, 256, 0, stream>>>(action, We1, be1, h1);
    gemm_rt<1, 0><<<dim3(2, B_N / 128), 256, 0, stream>>>(h1, We2, be2, h2, H_N, H_N, nullptr);
    gemm_rt<0, 0><<<dim3(1, B_N / 128), 256, 0, stream>>>(h2, We3, be3, z, H_N, D_N, nullptr);

    // np-exact squared norms
    rowsum_kernel<<<B_N / 256, 256, 0, stream>>>(z, az2);
    embsum_kernel<<<K_N / 256, 256, 0, stream>>>(emb, e2);

    // bf16 hi/lo splits
    split_kernel<<<(B_N * D_N / 4) / 256, 256, 0, stream>>>(z, zh, zl);
    split_kernel<<<(K_N * D_N / 4) / 256, 256, 0, stream>>>(emb, eh, el);

    // VQ: MFMA candidates (code-split) -> merge + margin + exact refine -> exact fallback
    hipMemsetAsync(flagcnt, 0, sizeof(int), stream);
    vq_mfma<<<dim3(CB_N, B_N / 64), 256, 0, stream>>>(zh, zl, eh, el, az2, e2, tw);
    vq_pick<<<B_N / 256, 256, 0, stream>>>(tw, z, emb, az2, e2, idxI, out + 3,
                                           flaglist, flagcnt);
    vq_fallback<<<256, 64, 0, stream>>>(z, emb, az2, e2, flaglist, flagcnt, idxI, out + 3);
    vqloss_kernel<<<B_N / 64, 256, 0, stream>>>(z, emb, idxI, vqp);

    // decoder (dec1 gathers q = emb[idx]; zh/zl and tw regions dead by their overwrite points)
    gemm_rt<1, 1><<<dim3(2, B_N / 128), 256, 0, stream>>>(emb, Wd1, bd1, h1, D_N, H_N, idxI);
    gemm_rt<1, 0><<<dim3(2, B_N / 128), 256, 0, stream>>>(h1, Wd2, bd2, h2, H_N, H_N, nullptr);

    // head + losses
    head_kernel<<<(B_N * A_N) / 256, 256, 0, stream>>>(h2, Wh, bh, action, out + 3 + B_N, recp);
    final_kernel<<<1, 64, 0, stream>>>(vqp, recp, out);
}

// Round 9
// 548.204 us; speedup vs baseline: 1.2968x; 1.2968x over previous
//
#include <hip/hip_runtime.h>
#include <math.h>

#define B_N 32768
#define A_N 6
#define H_N 256
#define D_N 128
#define K_N 2048
#define MU 1e-7f
#define CB_N 4          // code-dimension split of vq_mfma
#define CPC (K_N / CB_N)

typedef __attribute__((ext_vector_type(8))) short bf16x8;
typedef __attribute__((ext_vector_type(4))) float f32x4;

// Block compiler from contracting a*a into subsequent adds (np computes z*z array, then sums it)
__device__ __forceinline__ float sqf(float v) {
    float s = v * v;
    asm volatile("" : "+v"(s));
    return s;
}

// numpy pairwise_sum for n=128 contiguous fp32: 8 accumulators stride-8 + fixed 3-level tree.
// Bitwise replication of np.sum(x*x, axis=-1). PROTECTED SEMANTICS: do not alter the add order.
__device__ __forceinline__ float np_sumsq_128(const float* __restrict__ p)
{
    float r[8];
#pragma unroll
    for (int j = 0; j < 8; j++) r[j] = sqf(p[j]);
#pragma unroll
    for (int i = 8; i < 128; i += 8) {
#pragma unroll
        for (int j = 0; j < 8; j++) r[j] = r[j] + sqf(p[i + j]);
    }
    return ((r[0] + r[1]) + (r[2] + r[3])) + ((r[4] + r[5]) + (r[6] + r[7]));
}

__global__ __launch_bounds__(256) void rowsum_kernel(const float* __restrict__ z,
                                                     float* __restrict__ az2)
{
    int r = blockIdx.x * 256 + threadIdx.x;
    az2[r] = np_sumsq_128(z + (long)r * D_N);
}

__global__ __launch_bounds__(256) void embsum_kernel(const float* __restrict__ emb,
                                                     float* __restrict__ e2)
{
    int k = blockIdx.x * 256 + threadIdx.x;
    e2[k] = np_sumsq_128(emb + (long)k * D_N);
}

// ---------------- encoder layer 1 (protected fp32 fmaf chain) ----------------
__global__ __launch_bounds__(256) void enc1_kernel(const float* __restrict__ action,
    const float* __restrict__ W, const float* __restrict__ bias, float* __restrict__ out)
{
    __shared__ float as[8][6];
    int tid = threadIdx.x;
    int row0 = blockIdx.x * 8;
    if (tid < 48) as[tid / 6][tid % 6] = action[(long)(row0 + tid / 6) * A_N + tid % 6];
    __syncthreads();
    int col = tid;
    float w[6];
#pragma unroll
    for (int k = 0; k < 6; k++) w[k] = W[k * H_N + col];
    float bv = bias[col];
#pragma unroll
    for (int r = 0; r < 8; r++) {
        float acc = bv;
#pragma unroll
        for (int k = 0; k < 6; k++) acc = fmaf(as[r][k], w[k], acc);
        out[(long)(row0 + r) * H_N + col] = fmaxf(acc, 0.0f);
    }
}

// ---------------- register-tiled fp32 GEMM (R5 configuration, 128x128, 8x8) ----------------
// Per-acc chain: one fmaf per k, ascending == OpenBLAS semantics (z bits PROTECTED).
template<int RELU, int GATHER>
__global__ __launch_bounds__(256) void gemm_rt(const float* __restrict__ Amat,
    const float* __restrict__ W, const float* __restrict__ bias,
    float* __restrict__ Omat, int Kdim, int N, const int* __restrict__ gidx)
{
    __shared__ float As[16][132];   // k-major: As[k][row]
    __shared__ float Bs[16][132];   // k-major: Bs[k][col]
    int tid = threadIdx.x;
    int tx = tid & 15, ty = tid >> 4;
    int row0 = blockIdx.y * 128;
    int col0 = blockIdx.x * 128;
    float acc[8][8];
#pragma unroll
    for (int i = 0; i < 8; i++)
#pragma unroll
        for (int j = 0; j < 8; j++) acc[i][j] = 0.0f;

    for (int k0 = 0; k0 < Kdim; k0 += 16) {
        for (int f = tid; f < 512; f += 256) {
            int r = f >> 2, k4 = (f & 3) * 4;
            long arow = row0 + r;
            long abase = GATHER ? (long)gidx[arow] * Kdim : arow * (long)Kdim;
            float4 v = *(const float4*)&Amat[abase + k0 + k4];
            As[k4 + 0][r] = v.x; As[k4 + 1][r] = v.y; As[k4 + 2][r] = v.z; As[k4 + 3][r] = v.w;
        }
        for (int f = tid; f < 512; f += 256) {
            int kr = f >> 5, c4 = (f & 31) * 4;
            *(float4*)&Bs[kr][c4] = *(const float4*)&W[(long)(k0 + kr) * N + col0 + c4];
        }
        __syncthreads();
#pragma unroll
        for (int kk = 0; kk < 16; kk++) {
            float4 a0 = *(const float4*)&As[kk][ty * 8];
            float4 a1 = *(const float4*)&As[kk][ty * 8 + 4];
            float4 b0 = *(const float4*)&Bs[kk][tx * 4];
            float4 b1 = *(const float4*)&Bs[kk][64 + tx * 4];
            float av[8] = {a0.x, a0.y, a0.z, a0.w, a1.x, a1.y, a1.z, a1.w};
            float bv[8] = {b0.x, b0.y, b0.z, b0.w, b1.x, b1.y, b1.z, b1.w};
#pragma unroll
            for (int i = 0; i < 8; i++)
#pragma unroll
                for (int j = 0; j < 8; j++)
                    acc[i][j] = fmaf(av[i], bv[j], acc[i][j]);
        }
        __syncthreads();
    }
#pragma unroll
    for (int i = 0; i < 8; i++) {
        long r = row0 + ty * 8 + i;
        int c0 = col0 + tx * 4;
        int c1 = col0 + 64 + tx * 4;
        float4 o0, o1;
        o0.x = acc[i][0] + bias[c0 + 0];
        o0.y = acc[i][1] + bias[c0 + 1];
        o0.z = acc[i][2] + bias[c0 + 2];
        o0.w = acc[i][3] + bias[c0 + 3];
        o1.x = acc[i][4] + bias[c1 + 0];
        o1.y = acc[i][5] + bias[c1 + 1];
        o1.z = acc[i][6] + bias[c1 + 2];
        o1.w = acc[i][7] + bias[c1 + 3];
        if (RELU) {
            o0.x = fmaxf(o0.x, 0.0f); o0.y = fmaxf(o0.y, 0.0f);
            o0.z = fmaxf(o0.z, 0.0f); o0.w = fmaxf(o0.w, 0.0f);
            o1.x = fmaxf(o1.x, 0.0f); o1.y = fmaxf(o1.y, 0.0f);
            o1.z = fmaxf(o1.z, 0.0f); o1.w = fmaxf(o1.w, 0.0f);
        }
        *(float4*)&Omat[r * N + c0] = o0;
        *(float4*)&Omat[r * N + c1] = o1;
    }
}

// ---------------- bf16 hi/lo split ----------------
__device__ __forceinline__ unsigned short f2bf(float x) {
    unsigned u = __float_as_uint(x);
    u += 0x7fffu + ((u >> 16) & 1u);
    return (unsigned short)(u >> 16);
}
__device__ __forceinline__ float bf2f(unsigned short h) {
    return __uint_as_float(((unsigned)h) << 16);
}

__global__ __launch_bounds__(256) void split_kernel(const float* __restrict__ x,
    short* __restrict__ xh, short* __restrict__ xl)
{
    long i = (long)blockIdx.x * 256 + threadIdx.x;
    float4 v = *(const float4*)&x[i * 4];
    float vv[4] = {v.x, v.y, v.z, v.w};
    short hs[4], ls[4];
#pragma unroll
    for (int j = 0; j < 4; j++) {
        unsigned short h = f2bf(vv[j]);
        hs[j] = (short)h;
        ls[j] = (short)f2bf(vv[j] - bf2f(h));
    }
    ((short4*)xh)[i] = make_short4(hs[0], hs[1], hs[2], hs[3]);
    ((short4*)xl)[i] = make_short4(ls[0], ls[1], ls[2], ls[3]);
}

// ---------------- VQ candidates: LDS-shared emb tiles + bf16-split MFMA, branchless top-2 ----
// dot' = (zh.eh + zl.eh) + (zh.el); s' = (az2+e2) - 2 dot'; |s'-s_np| <= ~1e-9 << MU.
// Body shaped like the (non-spilling) R5 kernel: LDS staging, straight-line epilogue.
// Emb tile row stride = 17x16B units -> ds_read_b128 2-way max (free, m136).
__global__ __launch_bounds__(256, 2) void vq_mfma(const short* __restrict__ zh,
    const short* __restrict__ zl, const short* __restrict__ eh, const short* __restrict__ el,
    const float* __restrict__ az2, const float* __restrict__ e2,
    float2* __restrict__ tw /* [B][CB_N][2] = (val, idx-bits) */)
{
    __shared__ short ehs[16 * 136];   // 16 codes x 128 d, row stride 136 shorts
    __shared__ short els[16 * 136];
    int tid = threadIdx.x;
    int wave = tid >> 6, lane = tid & 63;
    int lo = lane & 15, hi = lane >> 4;
    int row0 = blockIdx.y * 64 + wave * 16;
    int code0 = blockIdx.x * CPC;
    int scode = tid >> 4, sq = tid & 15;   // staging: thread -> (code row, 16B unit)

    // resident A-frags: A row = lane&15, k = (lane>>4)*8 + elem (+ ks*32)  [validated R7]
    bf16x8 ahf[4], alf[4];
#pragma unroll
    for (int ks = 0; ks < 4; ks++) {
        long o = (long)(row0 + lo) * D_N + ks * 32 + hi * 8;
        ahf[ks] = *(const bf16x8*)&zh[o];
        alf[ks] = *(const bf16x8*)&zl[o];
    }
    float az_r[4];
#pragma unroll
    for (int r = 0; r < 4; r++) az_r[r] = az2[row0 + hi * 4 + r];

    float v1[4], v2[4];
    int   i1[4], i2[4];
#pragma unroll
    for (int r = 0; r < 4; r++) { v1[r] = v2[r] = 1e30f; i1[r] = i2[r] = 0; }

#pragma unroll 1
    for (int t = 0; t < CPC / 16; t++) {
        __syncthreads();
        {   // stage 16-code tile (hi+lo), coalesced 16B per thread per array
            long g = (long)(code0 + t * 16 + scode) * D_N + sq * 8;
            *(bf16x8*)&ehs[scode * 136 + sq * 8] = *(const bf16x8*)&eh[g];
            *(bf16x8*)&els[scode * 136 + sq * 8] = *(const bf16x8*)&el[g];
        }
        __syncthreads();
        int code = code0 + t * 16 + lo;      // B col = lane&15
        float e2v = e2[code];
        f32x4 a1 = {0.f, 0.f, 0.f, 0.f}, a2 = {0.f, 0.f, 0.f, 0.f};
#pragma unroll
        for (int ks = 0; ks < 4; ks++) {
            bf16x8 bh = *(const bf16x8*)&ehs[lo * 136 + ks * 32 + hi * 8];
            bf16x8 bl = *(const bf16x8*)&els[lo * 136 + ks * 32 + hi * 8];
            a1 = __builtin_amdgcn_mfma_f32_16x16x32_bf16(ahf[ks], bh, a1, 0, 0, 0);
            a2 = __builtin_amdgcn_mfma_f32_16x16x32_bf16(ahf[ks], bl, a2, 0, 0, 0);
            a1 = __builtin_amdgcn_mfma_f32_16x16x32_bf16(alf[ks], bh, a1, 0, 0, 0);
        }
#pragma unroll
        for (int r = 0; r < 4; r++) {
            float dot = a1[r] + a2[r];
            float s = (az_r[r] + e2v) - 2.0f * dot;
            // branchless top-2 insert; per-lane codes ascend -> strict < keeps first-min
            bool lt1 = s < v1[r];
            bool lt2 = s < v2[r];
            v2[r] = lt1 ? v1[r] : (lt2 ? s : v2[r]);
            i2[r] = lt1 ? i1[r] : (lt2 ? code : i2[r]);
            v1[r] = lt1 ? s : v1[r];
            i1[r] = lt1 ? code : i1[r];
        }
    }

    // branchless lex top-2 butterfly merge across the 16 lanes of each row-group
#pragma unroll
    for (int m = 1; m < 16; m <<= 1) {
#pragma unroll
        for (int r = 0; r < 4; r++) {
            float b1 = __shfl_xor(v1[r], m, 16); int j1 = __shfl_xor(i1[r], m, 16);
            float b2 = __shfl_xor(v2[r], m, 16); int j2 = __shfl_xor(i2[r], m, 16);
            bool bl = (b1 < v1[r]) || (b1 == v1[r] && j1 < i1[r]);
            float n1  = bl ? b1 : v1[r];  int n1i  = bl ? j1 : i1[r];
            float sc1 = bl ? v1[r] : b1;  int sc1i = bl ? i1[r] : j1;
            float sc2 = bl ? b2 : v2[r];  int sc2i = bl ? j2 : i2[r];
            bool s2 = (sc2 < sc1) || (sc2 == sc1 && sc2i < sc1i);
            v2[r] = s2 ? sc2 : sc1; i2[r] = s2 ? sc2i : sc1i;
            v1[r] = n1; i1[r] = n1i;
        }
    }
    if (lo == 0) {
#pragma unroll
        for (int r = 0; r < 4; r++) {
            long base = ((long)(row0 + hi * 4 + r) * CB_N + blockIdx.x) * 2;
            tw[base + 0] = make_float2(v1[r], __int_as_float(i1[r]));
            tw[base + 1] = make_float2(v2[r], __int_as_float(i2[r]));
        }
    }
}

// lex (v,i) insert into sorted top-2 (out of hot path)
__device__ __forceinline__ void ins2(float s, int c,
    float& v1, int& i1, float& v2, int& i2)
{
    if (s < v1 || (s == v1 && c < i1)) { v2 = v1; i2 = i1; v1 = s; i1 = c; }
    else if (s < v2 || (s == v2 && c < i2)) { v2 = s; i2 = c; }
}

// ---------------- merge partitions, certify with margin or flag for exact scan ------------
__global__ __launch_bounds__(256) void vq_pick(const float2* __restrict__ tw,
    int* __restrict__ idxI, float* __restrict__ outIdx,
    int* __restrict__ flaglist, int* __restrict__ flagcnt)
{
    int r = blockIdx.x * 256 + threadIdx.x;
    float v1 = 1e30f, v2 = 1e30f;
    int   i1 = 0, i2 = 0;
    for (int cb = 0; cb < CB_N; cb++) {
        float2 ca = tw[((long)r * CB_N + cb) * 2 + 0];
        float2 cb2 = tw[((long)r * CB_N + cb) * 2 + 1];
        ins2(ca.x, __float_as_int(ca.y), v1, i1, v2, i2);
        ins2(cb2.x, __float_as_int(cb2.y), v1, i1, v2, i2);
    }
    if (v2 <= v1 + MU) {          // cannot certify -> exact full scan
        int s = atomicAdd(flagcnt, 1);
        flaglist[s] = r;
    }
    idxI[r] = i1;
    outIdx[r] = (float)i1;
}

// ---------------- exact full scan for flagged rows (protected fp32 chain) ----------------
__global__ __launch_bounds__(64) void vq_fallback(const float* __restrict__ z,
    const float* __restrict__ emb, const float* __restrict__ az2, const float* __restrict__ e2,
    const int* __restrict__ flaglist, const int* __restrict__ flagcnt,
    int* __restrict__ idxI, float* __restrict__ outIdx)
{
    int n = *flagcnt;
    int lane = threadIdx.x;
    for (int i = blockIdx.x; i < n; i += gridDim.x) {
        int r = flaglist[i];
        const float* zr = z + (long)r * D_N;
        float az = az2[r];
        float bv = 1e30f; int bi = 0;
        for (int c = lane; c < K_N; c += 64) {
            const float* ec = emb + (long)c * D_N;
            float C = 0.0f;
            for (int d = 0; d < D_N; d++) C = fmaf(zr[d], ec[d], C);
            float d2 = (az + e2[c]) - 2.0f * C;
            if (d2 < bv) { bv = d2; bi = c; }   // ascending c: first-min
        }
#pragma unroll
        for (int m = 1; m < 64; m <<= 1) {
            float ov = __shfl_xor(bv, m, 64);
            int   oi = __shfl_xor(bi, m, 64);
            if (ov < bv || (ov == bv && oi < bi)) { bv = ov; bi = oi; }
        }
        if (lane == 0) { idxI[r] = bi; outIdx[r] = (float)bi; }
    }
}

// ---------------- vq loss partial sums ----------------
__global__ __launch_bounds__(256) void vqloss_kernel(const float* __restrict__ z,
    const float* __restrict__ emb, const int* __restrict__ idxI, float* __restrict__ part)
{
    __shared__ float red[256];
    int tid = threadIdx.x;
    int row0 = blockIdx.x * 64;
    float s = 0.0f;
    for (int e = tid; e < 64 * D_N; e += 256) {
        int r = row0 + (e >> 7), d = e & 127;
        float diff = z[(long)r * D_N + d] - emb[(long)idxI[r] * D_N + d];
        s = fmaf(diff, diff, s);
    }
    red[tid] = s; __syncthreads();
    for (int o = 128; o > 0; o >>= 1) { if (tid < o) red[tid] += red[tid + o]; __syncthreads(); }
    if (tid == 0) part[blockIdx.x] = red[0];
}

// ---------------- head: recons = tanh(d2 @ Wh + bh), partial recon loss ----------------
__global__ __launch_bounds__(256) void head_kernel(const float* __restrict__ dbuf,
    const float* __restrict__ Wh, const float* __restrict__ bh,
    const float* __restrict__ action, float* __restrict__ outRec, float* __restrict__ part)
{
    __shared__ float WhS[H_N * A_N];
    __shared__ float red[256];
    int tid = threadIdx.x;
    for (int i = tid; i < H_N * A_N; i += 256) WhS[i] = Wh[i];
    __syncthreads();
    long t = (long)blockIdx.x * 256 + tid;
    int row = (int)(t / 6), col = (int)(t % 6);
    const float* dr = dbuf + (long)row * H_N;
    float acc = bh[col];
    for (int k = 0; k < H_N; k++) acc = fmaf(dr[k], WhS[k * 6 + col], acc);
    float rec = tanhf(acc);
    outRec[t] = rec;
    float diff = rec - action[t];
    red[tid] = diff * diff;
    __syncthreads();
    for (int o = 128; o > 0; o >>= 1) { if (tid < o) red[tid] += red[tid + o]; __syncthreads(); }
    if (tid == 0) part[blockIdx.x] = red[0];
}

// ---------------- finalize scalars ----------------
__global__ void final_kernel(const float* __restrict__ vqp, const float* __restrict__ recp,
                             float* __restrict__ out)
{
    if (threadIdx.x == 0 && blockIdx.x == 0) {
        double vs = 0.0;
        for (int i = 0; i < 512; i++) vs += (double)vqp[i];
        double rs = 0.0;
        for (int i = 0; i < 768; i++) rs += (double)recp[i];
        double m = vs / 4194304.0;           // B*D
        double vql = 1.25 * m;               // beta*commit + embed (forward-equal)
        double rl = rs / 196608.0;           // B*A
        out[0] = (float)(rl + vql);
        out[1] = (float)vql;
        out[2] = (float)rl;
    }
}

extern "C" void kernel_launch(void* const* d_in, const int* in_sizes, int n_in,
                              void* d_out, int out_size, void* d_ws, size_t ws_size,
                              hipStream_t stream)
{
    (void)in_sizes; (void)n_in; (void)out_size; (void)ws_size;
    const float* action = (const float*)d_in[0];
    const float* We1 = (const float*)d_in[1];
    const float* be1 = (const float*)d_in[2];
    const float* We2 = (const float*)d_in[3];
    const float* be2 = (const float*)d_in[4];
    const float* We3 = (const float*)d_in[5];
    const float* be3 = (const float*)d_in[6];
    const float* emb = (const float*)d_in[7];
    const float* Wd1 = (const float*)d_in[8];
    const float* bd1 = (const float*)d_in[9];
    const float* Wd2 = (const float*)d_in[10];
    const float* bd2 = (const float*)d_in[11];
    const float* Wh  = (const float*)d_in[12];
    const float* bh  = (const float*)d_in[13];
    float* out = (float*)d_out;

    // workspace layout (~84 MB):
    //   h1 : B*H floats (33.5 MB) -- aliased as zh/zl/eh/el during VQ (dead post-enc2)
    //   h2 : B*H floats (33.5 MB) -- aliased as tw/flaglist/flagcnt (dead post-enc3)
    //   z  : B*D floats (16.8 MB)
    //   tail: az2(B) e2(K) idxI(B) vqp(512) recp(768)
    float* h1 = (float*)d_ws;
    float* h2 = h1 + (long)B_N * H_N;
    float* z  = h2 + (long)B_N * H_N;
    float* az2 = z + (long)B_N * D_N;
    float* e2  = az2 + B_N;
    int*   idxI = (int*)(e2 + K_N);
    float* vqp  = (float*)(idxI + B_N);
    float* recp = vqp + 512;

    short* zh = (short*)h1;                 // 8.4 MB
    short* zl = zh + (long)B_N * D_N;       // 8.4 MB
    short* eh = zl + (long)B_N * D_N;       // 0.5 MB
    short* el = eh + (long)K_N * D_N;       // 0.5 MB
    float2* tw = (float2*)h2;               // B*CB_N*2 float2 = 2.1 MB
    int* flaglist = (int*)(tw + (long)B_N * CB_N * 2);  // B ints
    int* flagcnt  = flaglist + B_N;                     // 1

    // encoder (protected fp32 chains)
    enc1_kernel<<<B_N / 8, 256, 0, stream>>>(action, We1, be1, h1);
    gemm_rt<1, 0><<<dim3(2, B_N / 128), 256, 0, stream>>>(h1, We2, be2, h2, H_N, H_N, nullptr);
    gemm_rt<0, 0><<<dim3(1, B_N / 128), 256, 0, stream>>>(h2, We3, be3, z, H_N, D_N, nullptr);

    // np-exact squared norms
    rowsum_kernel<<<B_N / 256, 256, 0, stream>>>(z, az2);
    embsum_kernel<<<K_N / 256, 256, 0, stream>>>(emb, e2);

    // bf16 hi/lo splits
    split_kernel<<<(B_N * D_N / 4) / 256, 256, 0, stream>>>(z, zh, zl);
    split_kernel<<<(K_N * D_N / 4) / 256, 256, 0, stream>>>(emb, eh, el);

    // VQ: MFMA candidates (LDS-shared emb) -> certify/flag -> exact fallback scan
    hipMemsetAsync(flagcnt, 0, sizeof(int), stream);
    vq_mfma<<<dim3(CB_N, B_N / 64), 256, 0, stream>>>(zh, zl, eh, el, az2, e2, tw);
    vq_pick<<<B_N / 256, 256, 0, stream>>>(tw, idxI, out + 3, flaglist, flagcnt);
    vq_fallback<<<2048, 64, 0, stream>>>(z, emb, az2, e2, flaglist, flagcnt, idxI, out + 3);
    vqloss_kernel<<<B_N / 64, 256, 0, stream>>>(z, emb, idxI, vqp);

    // decoder (dec1 gathers q = emb[idx]; zh/zl and tw regions dead by their overwrite points)
    gemm_rt<1, 1><<<dim3(2, B_N / 128), 256, 0, stream>>>(emb, Wd1, bd1, h1, D_N, H_N, idxI);
    gemm_rt<1, 0><<<dim3(2, B_N / 128), 256, 0, stream>>>(h1, Wd2, bd2, h2, H_N, H_N, nullptr);

    // head + losses
    head_kernel<<<(B_N * A_N) / 256, 256, 0, stream>>>(h2, Wh, bh, action, out + 3 + B_N, recp);
    final_kernel<<<1, 64, 0, stream>>>(vqp, recp, out);
}

// Round 10
// 496.823 us; speedup vs baseline: 1.4309x; 1.1034x over previous
//
#include <hip/hip_runtime.h>
#include <math.h>

#define B_N 32768
#define A_N 6
#define H_N 256
#define D_N 128
#define K_N 2048
#define MU 1e-7f
#define CB_N 4          // code-dimension split of vq_mfma
#define CPC (K_N / CB_N)
#define FB_ROWS 8       // flagged rows per fallback block

typedef __attribute__((ext_vector_type(8))) short bf16x8;
typedef __attribute__((ext_vector_type(4))) float f32x4;

// Block compiler from contracting a*a into subsequent adds (np computes z*z array, then sums it)
__device__ __forceinline__ float sqf(float v) {
    float s = v * v;
    asm volatile("" : "+v"(s));
    return s;
}

// numpy pairwise_sum for n=128 contiguous fp32: 8 accumulators stride-8 + fixed 3-level tree.
// Bitwise replication of np.sum(x*x, axis=-1). PROTECTED SEMANTICS: do not alter the add order.
__device__ __forceinline__ float np_sumsq_128(const float* __restrict__ p)
{
    float r[8];
#pragma unroll
    for (int j = 0; j < 8; j++) r[j] = sqf(p[j]);
#pragma unroll
    for (int i = 8; i < 128; i += 8) {
#pragma unroll
        for (int j = 0; j < 8; j++) r[j] = r[j] + sqf(p[i + j]);
    }
    return ((r[0] + r[1]) + (r[2] + r[3])) + ((r[4] + r[5]) + (r[6] + r[7]));
}

__global__ __launch_bounds__(256) void rowsum_kernel(const float* __restrict__ z,
                                                     float* __restrict__ az2)
{
    int r = blockIdx.x * 256 + threadIdx.x;
    az2[r] = np_sumsq_128(z + (long)r * D_N);
}

__global__ __launch_bounds__(256) void embsum_kernel(const float* __restrict__ emb,
                                                     float* __restrict__ e2)
{
    int k = blockIdx.x * 256 + threadIdx.x;
    e2[k] = np_sumsq_128(emb + (long)k * D_N);
}

// ---------------- encoder layer 1 (protected fp32 fmaf chain) ----------------
__global__ __launch_bounds__(256) void enc1_kernel(const float* __restrict__ action,
    const float* __restrict__ W, const float* __restrict__ bias, float* __restrict__ out)
{
    __shared__ float as[8][6];
    int tid = threadIdx.x;
    int row0 = blockIdx.x * 8;
    if (tid < 48) as[tid / 6][tid % 6] = action[(long)(row0 + tid / 6) * A_N + tid % 6];
    __syncthreads();
    int col = tid;
    float w[6];
#pragma unroll
    for (int k = 0; k < 6; k++) w[k] = W[k * H_N + col];
    float bv = bias[col];
#pragma unroll
    for (int r = 0; r < 8; r++) {
        float acc = bv;
#pragma unroll
        for (int k = 0; k < 6; k++) acc = fmaf(as[r][k], w[k], acc);
        out[(long)(row0 + r) * H_N + col] = fmaxf(acc, 0.0f);
    }
}

// ---------------- register-tiled fp32 GEMM (R5 configuration, 128x128, 8x8) ----------------
// Per-acc chain: one fmaf per k, ascending == OpenBLAS semantics (z bits PROTECTED).
template<int RELU, int GATHER>
__global__ __launch_bounds__(256) void gemm_rt(const float* __restrict__ Amat,
    const float* __restrict__ W, const float* __restrict__ bias,
    float* __restrict__ Omat, int Kdim, int N, const int* __restrict__ gidx)
{
    __shared__ float As[16][132];   // k-major: As[k][row]
    __shared__ float Bs[16][132];   // k-major: Bs[k][col]
    int tid = threadIdx.x;
    int tx = tid & 15, ty = tid >> 4;
    int row0 = blockIdx.y * 128;
    int col0 = blockIdx.x * 128;
    float acc[8][8];
#pragma unroll
    for (int i = 0; i < 8; i++)
#pragma unroll
        for (int j = 0; j < 8; j++) acc[i][j] = 0.0f;

    for (int k0 = 0; k0 < Kdim; k0 += 16) {
        for (int f = tid; f < 512; f += 256) {
            int r = f >> 2, k4 = (f & 3) * 4;
            long arow = row0 + r;
            long abase = GATHER ? (long)gidx[arow] * Kdim : arow * (long)Kdim;
            float4 v = *(const float4*)&Amat[abase + k0 + k4];
            As[k4 + 0][r] = v.x; As[k4 + 1][r] = v.y; As[k4 + 2][r] = v.z; As[k4 + 3][r] = v.w;
        }
        for (int f = tid; f < 512; f += 256) {
            int kr = f >> 5, c4 = (f & 31) * 4;
            *(float4*)&Bs[kr][c4] = *(const float4*)&W[(long)(k0 + kr) * N + col0 + c4];
        }
        __syncthreads();
#pragma unroll
        for (int kk = 0; kk < 16; kk++) {
            float4 a0 = *(const float4*)&As[kk][ty * 8];
            float4 a1 = *(const float4*)&As[kk][ty * 8 + 4];
            float4 b0 = *(const float4*)&Bs[kk][tx * 4];
            float4 b1 = *(const float4*)&Bs[kk][64 + tx * 4];
            float av[8] = {a0.x, a0.y, a0.z, a0.w, a1.x, a1.y, a1.z, a1.w};
            float bv[8] = {b0.x, b0.y, b0.z, b0.w, b1.x, b1.y, b1.z, b1.w};
#pragma unroll
            for (int i = 0; i < 8; i++)
#pragma unroll
                for (int j = 0; j < 8; j++)
                    acc[i][j] = fmaf(av[i], bv[j], acc[i][j]);
        }
        __syncthreads();
    }
#pragma unroll
    for (int i = 0; i < 8; i++) {
        long r = row0 + ty * 8 + i;
        int c0 = col0 + tx * 4;
        int c1 = col0 + 64 + tx * 4;
        float4 o0, o1;
        o0.x = acc[i][0] + bias[c0 + 0];
        o0.y = acc[i][1] + bias[c0 + 1];
        o0.z = acc[i][2] + bias[c0 + 2];
        o0.w = acc[i][3] + bias[c0 + 3];
        o1.x = acc[i][4] + bias[c1 + 0];
        o1.y = acc[i][5] + bias[c1 + 1];
        o1.z = acc[i][6] + bias[c1 + 2];
        o1.w = acc[i][7] + bias[c1 + 3];
        if (RELU) {
            o0.x = fmaxf(o0.x, 0.0f); o0.y = fmaxf(o0.y, 0.0f);
            o0.z = fmaxf(o0.z, 0.0f); o0.w = fmaxf(o0.w, 0.0f);
            o1.x = fmaxf(o1.x, 0.0f); o1.y = fmaxf(o1.y, 0.0f);
            o1.z = fmaxf(o1.z, 0.0f); o1.w = fmaxf(o1.w, 0.0f);
        }
        *(float4*)&Omat[r * N + c0] = o0;
        *(float4*)&Omat[r * N + c1] = o1;
    }
}

// ---------------- bf16 hi/lo split ----------------
__device__ __forceinline__ unsigned short f2bf(float x) {
    unsigned u = __float_as_uint(x);
    u += 0x7fffu + ((u >> 16) & 1u);
    return (unsigned short)(u >> 16);
}
__device__ __forceinline__ float bf2f(unsigned short h) {
    return __uint_as_float(((unsigned)h) << 16);
}

__global__ __launch_bounds__(256) void split_kernel(const float* __restrict__ x,
    short* __restrict__ xh, short* __restrict__ xl)
{
    long i = (long)blockIdx.x * 256 + threadIdx.x;
    float4 v = *(const float4*)&x[i * 4];
    float vv[4] = {v.x, v.y, v.z, v.w};
    short hs[4], ls[4];
#pragma unroll
    for (int j = 0; j < 4; j++) {
        unsigned short h = f2bf(vv[j]);
        hs[j] = (short)h;
        ls[j] = (short)f2bf(vv[j] - bf2f(h));
    }
    ((short4*)xh)[i] = make_short4(hs[0], hs[1], hs[2], hs[3]);
    ((short4*)xl)[i] = make_short4(ls[0], ls[1], ls[2], ls[3]);
}

// ---------------- VQ candidates: LDS-shared emb tiles + bf16-split MFMA, branchless top-2 ----
// dot' = (zh.eh + zl.eh) + (zh.el); s' = (az2+e2) - 2 dot'; |s'-s_np| <= ~4e-9 << MU.
// (unchanged from R9 -- validated, no longer in top-5)
__global__ __launch_bounds__(256, 2) void vq_mfma(const short* __restrict__ zh,
    const short* __restrict__ zl, const short* __restrict__ eh, const short* __restrict__ el,
    const float* __restrict__ az2, const float* __restrict__ e2,
    float2* __restrict__ tw /* [B][CB_N][2] = (val, idx-bits) */)
{
    __shared__ short ehs[16 * 136];   // 16 codes x 128 d, row stride 136 shorts
    __shared__ short els[16 * 136];
    int tid = threadIdx.x;
    int wave = tid >> 6, lane = tid & 63;
    int lo = lane & 15, hi = lane >> 4;
    int row0 = blockIdx.y * 64 + wave * 16;
    int code0 = blockIdx.x * CPC;
    int scode = tid >> 4, sq = tid & 15;   // staging: thread -> (code row, 16B unit)

    // resident A-frags: A row = lane&15, k = (lane>>4)*8 + elem (+ ks*32)  [validated R7]
    bf16x8 ahf[4], alf[4];
#pragma unroll
    for (int ks = 0; ks < 4; ks++) {
        long o = (long)(row0 + lo) * D_N + ks * 32 + hi * 8;
        ahf[ks] = *(const bf16x8*)&zh[o];
        alf[ks] = *(const bf16x8*)&zl[o];
    }
    float az_r[4];
#pragma unroll
    for (int r = 0; r < 4; r++) az_r[r] = az2[row0 + hi * 4 + r];

    float v1[4], v2[4];
    int   i1[4], i2[4];
#pragma unroll
    for (int r = 0; r < 4; r++) { v1[r] = v2[r] = 1e30f; i1[r] = i2[r] = 0; }

#pragma unroll 1
    for (int t = 0; t < CPC / 16; t++) {
        __syncthreads();
        {   // stage 16-code tile (hi+lo), coalesced 16B per thread per array
            long g = (long)(code0 + t * 16 + scode) * D_N + sq * 8;
            *(bf16x8*)&ehs[scode * 136 + sq * 8] = *(const bf16x8*)&eh[g];
            *(bf16x8*)&els[scode * 136 + sq * 8] = *(const bf16x8*)&el[g];
        }
        __syncthreads();
        int code = code0 + t * 16 + lo;      // B col = lane&15
        float e2v = e2[code];
        f32x4 a1 = {0.f, 0.f, 0.f, 0.f}, a2 = {0.f, 0.f, 0.f, 0.f};
#pragma unroll
        for (int ks = 0; ks < 4; ks++) {
            bf16x8 bh = *(const bf16x8*)&ehs[lo * 136 + ks * 32 + hi * 8];
            bf16x8 bl = *(const bf16x8*)&els[lo * 136 + ks * 32 + hi * 8];
            a1 = __builtin_amdgcn_mfma_f32_16x16x32_bf16(ahf[ks], bh, a1, 0, 0, 0);
            a2 = __builtin_amdgcn_mfma_f32_16x16x32_bf16(ahf[ks], bl, a2, 0, 0, 0);
            a1 = __builtin_amdgcn_mfma_f32_16x16x32_bf16(alf[ks], bh, a1, 0, 0, 0);
        }
#pragma unroll
        for (int r = 0; r < 4; r++) {
            float dot = a1[r] + a2[r];
            float s = (az_r[r] + e2v) - 2.0f * dot;
            // branchless top-2 insert; per-lane codes ascend -> strict < keeps first-min
            bool lt1 = s < v1[r];
            bool lt2 = s < v2[r];
            v2[r] = lt1 ? v1[r] : (lt2 ? s : v2[r]);
            i2[r] = lt1 ? i1[r] : (lt2 ? code : i2[r]);
            v1[r] = lt1 ? s : v1[r];
            i1[r] = lt1 ? code : i1[r];
        }
    }

    // branchless lex top-2 butterfly merge across the 16 lanes of each row-group
#pragma unroll
    for (int m = 1; m < 16; m <<= 1) {
#pragma unroll
        for (int r = 0; r < 4; r++) {
            float b1 = __shfl_xor(v1[r], m, 16); int j1 = __shfl_xor(i1[r], m, 16);
            float b2 = __shfl_xor(v2[r], m, 16); int j2 = __shfl_xor(i2[r], m, 16);
            bool bl = (b1 < v1[r]) || (b1 == v1[r] && j1 < i1[r]);
            float n1  = bl ? b1 : v1[r];  int n1i  = bl ? j1 : i1[r];
            float sc1 = bl ? v1[r] : b1;  int sc1i = bl ? i1[r] : j1;
            float sc2 = bl ? b2 : v2[r];  int sc2i = bl ? j2 : i2[r];
            bool s2 = (sc2 < sc1) || (sc2 == sc1 && sc2i < sc1i);
            v2[r] = s2 ? sc2 : sc1; i2[r] = s2 ? sc2i : sc1i;
            v1[r] = n1; i1[r] = n1i;
        }
    }
    if (lo == 0) {
#pragma unroll
        for (int r = 0; r < 4; r++) {
            long base = ((long)(row0 + hi * 4 + r) * CB_N + blockIdx.x) * 2;
            tw[base + 0] = make_float2(v1[r], __int_as_float(i1[r]));
            tw[base + 1] = make_float2(v2[r], __int_as_float(i2[r]));
        }
    }
}

// lex (v,i) insert into sorted top-2 (out of hot path)
__device__ __forceinline__ void ins2(float s, int c,
    float& v1, int& i1, float& v2, int& i2)
{
    if (s < v1 || (s == v1 && c < i1)) { v2 = v1; i2 = i1; v1 = s; i1 = c; }
    else if (s < v2 || (s == v2 && c < i2)) { v2 = s; i2 = c; }
}

// ---------------- merge partitions, certify with margin or flag for exact scan ------------
__global__ __launch_bounds__(256) void vq_pick(const float2* __restrict__ tw,
    int* __restrict__ idxI, float* __restrict__ outIdx,
    int* __restrict__ flaglist, int* __restrict__ flagcnt)
{
    int r = blockIdx.x * 256 + threadIdx.x;
    float v1 = 1e30f, v2 = 1e30f;
    int   i1 = 0, i2 = 0;
    for (int cb = 0; cb < CB_N; cb++) {
        float2 ca = tw[((long)r * CB_N + cb) * 2 + 0];
        float2 cb2 = tw[((long)r * CB_N + cb) * 2 + 1];
        ins2(ca.x, __float_as_int(ca.y), v1, i1, v2, i2);
        ins2(cb2.x, __float_as_int(cb2.y), v1, i1, v2, i2);
    }
    if (v2 <= v1 + MU) {          // cannot certify -> exact full scan
        int s = atomicAdd(flagcnt, 1);
        flaglist[s] = r;
    }
    idxI[r] = i1;
    outIdx[r] = (float)i1;
}

// ---------------- exact full scan for flagged rows, LDS-batched ----------------
// 8 rows/block; emb staged in 64-code LDS tiles (stride 129 -> es reads 2-way = free,
// zs reads broadcast). Each wave owns 2 rows x 64 codes: two interleaved EXACT
// ascending-d fmaf chains (protected np semantics). 64-lane lex-min butterfly per row.
// Padded slots recompute a duplicate row deterministically (idempotent writes).
__global__ __launch_bounds__(256) void vq_fallback(const float* __restrict__ z,
    const float* __restrict__ emb, const float* __restrict__ az2, const float* __restrict__ e2,
    const int* __restrict__ flaglist, const int* __restrict__ flagcnt,
    int* __restrict__ idxI, float* __restrict__ outIdx)
{
    __shared__ float es[64][129];
    __shared__ float zs[FB_ROWS][128];
    __shared__ int rowids[FB_ROWS];
    int n = *flagcnt;
    int tid = threadIdx.x;
    int wave = tid >> 6, lane = tid & 63;
    for (int batch = blockIdx.x; batch * FB_ROWS < n; batch += gridDim.x) {
        __syncthreads();                       // protect zs/rowids reuse across batches
        if (tid < FB_ROWS) {
            int ri = batch * FB_ROWS + tid;
            rowids[tid] = flaglist[ri < n ? ri : n - 1];
        }
        __syncthreads();
        for (int f = tid; f < FB_ROWS * 128; f += 256) {
            int slot = f >> 7, d = f & 127;
            zs[slot][d] = z[(long)rowids[slot] * D_N + d];
        }
        int r0 = wave * 2, r1 = wave * 2 + 1;
        float bv0 = 1e30f, bv1 = 1e30f; int bi0 = 0, bi1 = 0;
        __syncthreads();                       // zs ready
        float az0 = az2[rowids[r0]];
        float az1 = az2[rowids[r1]];
        for (int t = 0; t < K_N / 64; t++) {
            __syncthreads();                   // previous tile's reads done
            for (int f = tid; f < 64 * 32; f += 256) {
                int c = f >> 5, q = f & 31;
                float4 v = *(const float4*)&emb[((long)(t * 64 + c)) * D_N + q * 4];
                es[c][q * 4 + 0] = v.x; es[c][q * 4 + 1] = v.y;
                es[c][q * 4 + 2] = v.z; es[c][q * 4 + 3] = v.w;
            }
            __syncthreads();                   // tile staged
            int code = t * 64 + lane;
            float C0 = 0.0f, C1 = 0.0f;
            for (int d = 0; d < D_N; d++) {
                float ev = es[lane][d];
                C0 = fmaf(zs[r0][d], ev, C0);  // exact ascending-d chain (PROTECTED)
                C1 = fmaf(zs[r1][d], ev, C1);
            }
            float e2v = e2[code];
            float d20 = (az0 + e2v) - 2.0f * C0;
            float d21 = (az1 + e2v) - 2.0f * C1;
            if (d20 < bv0) { bv0 = d20; bi0 = code; }   // tiles ascend -> first-min
            if (d21 < bv1) { bv1 = d21; bi1 = code; }
        }
#pragma unroll
        for (int m = 1; m < 64; m <<= 1) {
            float ov = __shfl_xor(bv0, m, 64); int oi = __shfl_xor(bi0, m, 64);
            if (ov < bv0 || (ov == bv0 && oi < bi0)) { bv0 = ov; bi0 = oi; }
            ov = __shfl_xor(bv1, m, 64); oi = __shfl_xor(bi1, m, 64);
            if (ov < bv1 || (ov == bv1 && oi < bi1)) { bv1 = ov; bi1 = oi; }
        }
        if (lane == 0) {
            idxI[rowids[r0]] = bi0; outIdx[rowids[r0]] = (float)bi0;
            idxI[rowids[r1]] = bi1; outIdx[rowids[r1]] = (float)bi1;
        }
    }
}

// ---------------- vq loss partial sums ----------------
__global__ __launch_bounds__(256) void vqloss_kernel(const float* __restrict__ z,
    const float* __restrict__ emb, const int* __restrict__ idxI, float* __restrict__ part)
{
    __shared__ float red[256];
    int tid = threadIdx.x;
    int row0 = blockIdx.x * 64;
    float s = 0.0f;
    for (int e = tid; e < 64 * D_N; e += 256) {
        int r = row0 + (e >> 7), d = e & 127;
        float diff = z[(long)r * D_N + d] - emb[(long)idxI[r] * D_N + d];
        s = fmaf(diff, diff, s);
    }
    red[tid] = s; __syncthreads();
    for (int o = 128; o > 0; o >>= 1) { if (tid < o) red[tid] += red[tid + o]; __syncthreads(); }
    if (tid == 0) part[blockIdx.x] = red[0];
}

// ---------------- head: recons = tanh(d2 @ Wh + bh), partial recon loss ----------------
__global__ __launch_bounds__(256) void head_kernel(const float* __restrict__ dbuf,
    const float* __restrict__ Wh, const float* __restrict__ bh,
    const float* __restrict__ action, float* __restrict__ outRec, float* __restrict__ part)
{
    __shared__ float WhS[H_N * A_N];
    __shared__ float red[256];
    int tid = threadIdx.x;
    for (int i = tid; i < H_N * A_N; i += 256) WhS[i] = Wh[i];
    __syncthreads();
    long t = (long)blockIdx.x * 256 + tid;
    int row = (int)(t / 6), col = (int)(t % 6);
    const float* dr = dbuf + (long)row * H_N;
    float acc = bh[col];
    for (int k = 0; k < H_N; k++) acc = fmaf(dr[k], WhS[k * 6 + col], acc);
    float rec = tanhf(acc);
    outRec[t] = rec;
    float diff = rec - action[t];
    red[tid] = diff * diff;
    __syncthreads();
    for (int o = 128; o > 0; o >>= 1) { if (tid < o) red[tid] += red[tid + o]; __syncthreads(); }
    if (tid == 0) part[blockIdx.x] = red[0];
}

// ---------------- finalize scalars ----------------
__global__ void final_kernel(const float* __restrict__ vqp, const float* __restrict__ recp,
                             float* __restrict__ out)
{
    if (threadIdx.x == 0 && blockIdx.x == 0) {
        double vs = 0.0;
        for (int i = 0; i < 512; i++) vs += (double)vqp[i];
        double rs = 0.0;
        for (int i = 0; i < 768; i++) rs += (double)recp[i];
        double m = vs / 4194304.0;           // B*D
        double vql = 1.25 * m;               // beta*commit + embed (forward-equal)
        double rl = rs / 196608.0;           // B*A
        out[0] = (float)(rl + vql);
        out[1] = (float)vql;
        out[2] = (float)rl;
    }
}

extern "C" void kernel_launch(void* const* d_in, const int* in_sizes, int n_in,
                              void* d_out, int out_size, void* d_ws, size_t ws_size,
                              hipStream_t stream)
{
    (void)in_sizes; (void)n_in; (void)out_size; (void)ws_size;
    const float* action = (const float*)d_in[0];
    const float* We1 = (const float*)d_in[1];
    const float* be1 = (const float*)d_in[2];
    const float* We2 = (const float*)d_in[3];
    const float* be2 = (const float*)d_in[4];
    const float* We3 = (const float*)d_in[5];
    const float* be3 = (const float*)d_in[6];
    const float* emb = (const float*)d_in[7];
    const float* Wd1 = (const float*)d_in[8];
    const float* bd1 = (const float*)d_in[9];
    const float* Wd2 = (const float*)d_in[10];
    const float* bd2 = (const float*)d_in[11];
    const float* Wh  = (const float*)d_in[12];
    const float* bh  = (const float*)d_in[13];
    float* out = (float*)d_out;

    // workspace layout (~84 MB):
    //   h1 : B*H floats (33.5 MB) -- aliased as zh/zl/eh/el during VQ (dead post-enc2)
    //   h2 : B*H floats (33.5 MB) -- aliased as tw/flaglist/flagcnt (dead post-enc3)
    //   z  : B*D floats (16.8 MB)
    //   tail: az2(B) e2(K) idxI(B) vqp(512) recp(768)
    float* h1 = (float*)d_ws;
    float* h2 = h1 + (long)B_N * H_N;
    float* z  = h2 + (long)B_N * H_N;
    float* az2 = z + (long)B_N * D_N;
    float* e2  = az2 + B_N;
    int*   idxI = (int*)(e2 + K_N);
    float* vqp  = (float*)(idxI + B_N);
    float* recp = vqp + 512;

    short* zh = (short*)h1;                 // 8.4 MB
    short* zl = zh + (long)B_N * D_N;       // 8.4 MB
    short* eh = zl + (long)B_N * D_N;       // 0.5 MB
    short* el = eh + (long)K_N * D_N;       // 0.5 MB
    float2* tw = (float2*)h2;               // B*CB_N*2 float2 = 2.1 MB
    int* flaglist = (int*)(tw + (long)B_N * CB_N * 2);  // B ints
    int* flagcnt  = flaglist + B_N;                     // 1

    // encoder (protected fp32 chains)
    enc1_kernel<<<B_N / 8, 256, 0, stream>>>(action, We1, be1, h1);
    gemm_rt<1, 0><<<dim3(2, B_N / 128), 256, 0, stream>>>(h1, We2, be2, h2, H_N, H_N, nullptr);
    gemm_rt<0, 0><<<dim3(1, B_N / 128), 256, 0, stream>>>(h2, We3, be3, z, H_N, D_N, nullptr);

    // np-exact squared norms
    rowsum_kernel<<<B_N / 256, 256, 0, stream>>>(z, az2);
    embsum_kernel<<<K_N / 256, 256, 0, stream>>>(emb, e2);

    // bf16 hi/lo splits
    split_kernel<<<(B_N * D_N / 4) / 256, 256, 0, stream>>>(z, zh, zl);
    split_kernel<<<(K_N * D_N / 4) / 256, 256, 0, stream>>>(emb, eh, el);

    // VQ: MFMA candidates (LDS-shared emb) -> certify/flag -> exact fallback scan (batched)
    hipMemsetAsync(flagcnt, 0, sizeof(int), stream);
    vq_mfma<<<dim3(CB_N, B_N / 64), 256, 0, stream>>>(zh, zl, eh, el, az2, e2, tw);
    vq_pick<<<B_N / 256, 256, 0, stream>>>(tw, idxI, out + 3, flaglist, flagcnt);
    vq_fallback<<<512, 256, 0, stream>>>(z, emb, az2, e2, flaglist, flagcnt, idxI, out + 3);
    vqloss_kernel<<<B_N / 64, 256, 0, stream>>>(z, emb, idxI, vqp);

    // decoder (dec1 gathers q = emb[idx]; zh/zl and tw regions dead by their overwrite points)
    gemm_rt<1, 1><<<dim3(2, B_N / 128), 256, 0, stream>>>(emb, Wd1, bd1, h1, D_N, H_N, idxI);
    gemm_rt<1, 0><<<dim3(2, B_N / 128), 256, 0, stream>>>(h1, Wd2, bd2, h2, H_N, H_N, nullptr);

    // head + losses
    head_kernel<<<(B_N * A_N) / 256, 256, 0, stream>>>(h2, Wh, bh, action, out + 3 + B_N, recp);
    final_kernel<<<1, 64, 0, stream>>>(vqp, recp, out);
}